// Round 9
// baseline (92.733 us; speedup 1.0000x reference)
//
#include <hip/hip_runtime.h>

// Closed-form constant-curvature rollout, two-phase.
//
// State y = [r(3), R(9 row-major), ux, uy]; per segment ux,uy const:
//   R(s) = R0 * exp(s*uhat),  exp = I + A*uhat + B*uhat^2,
//   A = sin(phi)/theta, B = (1-cos(phi))/theta^2, phi = s*theta,
//   r(s) = r0 + R0 * (B*uy, -B*ux, A).
// Reference clamps at kmax = (int)(l/DS): s = min(t,kmax)*DS; next segment
// starts at s_end = kmax*DS.
//
// Phase 1 (tiny): per batch element, walk the 3-segment chain ONCE; store
// per-seg start state r0,R0 + ux,uy,kmax into d_ws, SoA [seg][field][b]
// (3*16*B floats = 3 MB) so phase 2 reads are stride-4B coalesced.
// Phase 2: one Rodrigues + one compose per output state; block output
// (256 x 14 floats = 14336 B contiguous) staged in LDS, streamed out as
// non-temporal 16B stores (native vector type: __builtin_nontemporal_store
// rejects HIP_vector_type float4).

namespace {

typedef float f32x4 __attribute__((ext_vector_type(4)));

constexpr float kL0 = 0.1f;
constexpr float kD  = 0.0075f;
constexpr float kDS = 0.005f;
constexpr int   kT    = 29;   // round((0.1+0.04)/0.005)+1
constexpr int   kNSeg = 3;
constexpr int   kF    = 16;   // SoA fields per (seg,b); 15 used, 16 for stride

__device__ __forceinline__ float fast_rcp(float x) {
    return __builtin_amdgcn_rcpf(x);   // v_rcp_f32, ~1 ulp
}

__device__ __forceinline__ void exp_and_p(float ux, float uy, float s,
                                          float E[9], float p[3]) {
    float th2   = ux * ux + uy * uy;
    float theta = sqrtf(th2);
    float A, Bv, c;
    if (theta < 1e-5f) {
        A  = s;
        Bv = 0.5f * s * s;
        c  = 1.0f;
    } else {
        float phi = s * theta;              // phi <= ~2.7 rad
        float sh, ch;
        __sincosf(0.5f * phi, &sh, &ch);    // native v_sin/v_cos
        float si  = 2.0f * sh * ch;         // sin(phi)
        float sh2 = 2.0f * sh * sh;         // 1 - cos(phi), no cancellation
        float rth = fast_rcp(theta);
        A  = si * rth;
        Bv = sh2 * rth * rth;
        c  = 1.0f - sh2;
    }
    float Aux = A * ux, Auy = A * uy;
    E[0] = 1.0f - Bv * uy * uy;
    E[1] = Bv * ux * uy;
    E[2] = Auy;
    E[3] = E[1];
    E[4] = 1.0f - Bv * ux * ux;
    E[5] = -Aux;
    E[6] = -Auy;
    E[7] = Aux;
    E[8] = c;
    p[0] = Bv * uy;
    p[1] = -Bv * ux;
    p[2] = A;
}

__device__ __forceinline__ void compose(const float r0[3], const float R0[9],
                                        const float E[9], const float p[3],
                                        float r[3], float R[9]) {
#pragma unroll
    for (int i = 0; i < 3; ++i) {
        r[i] = r0[i] + R0[3*i+0] * p[0] + R0[3*i+1] * p[1] + R0[3*i+2] * p[2];
#pragma unroll
        for (int j = 0; j < 3; ++j) {
            R[3*i+j] = R0[3*i+0] * E[j] + R0[3*i+1] * E[3+j] + R0[3*i+2] * E[6+j];
        }
    }
}

// ---------------- Phase 1: per-batch chain precompute (64 blocks) ----------
__global__ __launch_bounds__(256) void precompute(const float* __restrict__ actions,
                                                  float* __restrict__ W, int B) {
    int b = blockIdx.x * 256 + threadIdx.x;
    if (b >= B) return;

    float r[3] = {0.f, 0.f, 0.f};
    float R[9] = {1.f, 0.f, 0.f, 0.f, 1.f, 0.f, 0.f, 0.f, 1.f};

#pragma unroll
    for (int m = 0; m < kNSeg; ++m) {
        const float a0 = actions[b * 9 + 3 * m + 0];
        const float a1 = actions[b * 9 + 3 * m + 1];
        const float a2 = actions[b * 9 + 3 * m + 2];
        float l   = kL0 + a0;           // f32 add, matches jnp
        float md  = l * kD;
        float rmd = fast_rcp(md);
        float ux  = -a2 * rmd;
        float uy  = a1 * rmd;
        int kmax  = (int)(l / kDS);     // exact IEEE div + trunc == astype(int32)

        // store this segment's START state + params, SoA [seg][field][b]
        size_t base = (size_t)(m * kF) * (size_t)B + (size_t)b;
        W[base + 0 * (size_t)B] = r[0];
        W[base + 1 * (size_t)B] = r[1];
        W[base + 2 * (size_t)B] = r[2];
#pragma unroll
        for (int i = 0; i < 9; ++i) W[base + (size_t)(3 + i) * (size_t)B] = R[i];
        W[base + 12 * (size_t)B] = ux;
        W[base + 13 * (size_t)B] = uy;
        W[base + 14 * (size_t)B] = (float)kmax;

        if (m < kNSeg - 1) {            // advance frame to segment end
            float s = (float)kmax * kDS;
            float E[9], p[3];
            exp_and_p(ux, uy, s, E, p);
            float nr[3], NR[9];
            compose(r, R, E, p, nr, NR);
#pragma unroll
            for (int i = 0; i < 3; ++i) r[i] = nr[i];
#pragma unroll
            for (int i = 0; i < 9; ++i) R[i] = NR[i];
        }
    }
}

// ---------------- Phase 2: one state per thread (64 x 87 blocks) -----------
__global__ __launch_bounds__(256) void rollout(const float* __restrict__ W,
                                               float* __restrict__ out, int B) {
    __shared__ float smem[256 * 14];

    int b   = blockIdx.x * 256 + threadIdx.x;   // B % 256 == 0
    int row = blockIdx.y;                        // uniform per block
    int n   = (row >= 2 * kT) ? 2 : (row >= kT ? 1 : 0);
    int t   = row - n * kT;

    size_t base = (size_t)(n * kF) * (size_t)B + (size_t)b;
    float r0[3], R0[9];
    r0[0] = W[base + 0 * (size_t)B];
    r0[1] = W[base + 1 * (size_t)B];
    r0[2] = W[base + 2 * (size_t)B];
#pragma unroll
    for (int i = 0; i < 9; ++i) R0[i] = W[base + (size_t)(3 + i) * (size_t)B];
    float ux = W[base + 12 * (size_t)B];
    float uy = W[base + 13 * (size_t)B];
    int kmax = (int)W[base + 14 * (size_t)B];

    int tc  = t < kmax ? t : kmax;
    float s = (float)tc * kDS;

    float E[9], p[3];
    exp_and_p(ux, uy, s, E, p);
    float r[3], R[9];
    compose(r0, R0, E, p, r, R);

    // stage 14 outputs in LDS (stride 14: 4-way conflict, negligible count)
    float* my = &smem[threadIdx.x * 14];
    my[0] = r[0];  my[1] = r[1];  my[2] = r[2];
#pragma unroll
    for (int i = 0; i < 9; ++i) my[3 + i] = R[i];
    my[12] = ux;
    my[13] = uy;
    __syncthreads();

    // coalesced non-temporal block store: 256*14 floats = 896 x 16B
    size_t blockbase = ((size_t)row * (size_t)B + (size_t)blockIdx.x * 256) * 14;
    f32x4* o4 = reinterpret_cast<f32x4*>(out + blockbase);
    const f32x4* s4 = reinterpret_cast<const f32x4*>(smem);
#pragma unroll
    for (int k = 0; k < 3; ++k) {
        int q = k * 256 + threadIdx.x;
        __builtin_nontemporal_store(s4[q], &o4[q]);
    }
    if (threadIdx.x < 128) {
        int q = 768 + threadIdx.x;
        __builtin_nontemporal_store(s4[q], &o4[q]);
    }
}

} // namespace

extern "C" void kernel_launch(void* const* d_in, const int* in_sizes, int n_in,
                              void* d_out, int out_size, void* d_ws, size_t ws_size,
                              hipStream_t stream) {
    const float* actions = (const float*)d_in[0];
    float* out = (float*)d_out;
    float* W   = (float*)d_ws;               // 3*16*B floats = 3 MB, ws is >>
    int B = in_sizes[0] / 9;                 // 16384

    dim3 block(256);
    precompute<<<dim3((B + 255) / 256), block, 0, stream>>>(actions, W, B);
    rollout<<<dim3((B + 255) / 256, kNSeg * kT), block, 0, stream>>>(W, out, B);
}

// Round 10
// 91.050 us; speedup vs baseline: 1.0185x; 1.0185x over previous
//
#include <hip/hip_runtime.h>

// Closed-form constant-curvature rollout — single fused kernel.
//
// State y = [r(3), R(9 row-major), ux, uy]; per segment ux,uy const:
//   R(s) = R0 * exp(s*uhat),  exp = I + A*uhat + B*uhat^2,
//   A = sin(phi)/theta, B = (1-cos(phi))/theta^2, phi = s*theta,
//   r(s) = r0 + R0 * (B*uy, -B*ux, A).
// Reference clamps at kmax = (int)(l/DS): s = min(t,kmax)*DS; next segment
// starts at s_end = kmax*DS.
//
// Structure (R9 post-mortem: W-table re-reads + tiny per-block store bursts
// were the residual cost):
//   grid = (B/256 chunks, 3 segs * 6 row-groups). Block = 256 threads = 256
//   batch elements. Per block: coalesced-stage 256x9 actions into LDS; walk
//   the chain IN REGISTERS up to segment n (uniform, static-unrolled);
//   then for each of its 4-5 rows: one Rodrigues+compose, stage 256x14
//   floats in LDS, stream the contiguous 14336B slab as NT float4s.
// No workspace, no second kernel, no cross-row recompute beyond the cheap
// in-reg chain (<=2 advances).

namespace {

typedef float f32x4 __attribute__((ext_vector_type(4)));

constexpr float kL0 = 0.1f;
constexpr float kD  = 0.0075f;
constexpr float kDS = 0.005f;
constexpr int   kT    = 29;   // rows per segment
constexpr int   kNSeg = 3;
constexpr int   kGS   = 6;    // row-groups per segment

__device__ __forceinline__ float fast_rcp(float x) {
    return __builtin_amdgcn_rcpf(x);   // v_rcp_f32, ~1 ulp
}

__device__ __forceinline__ void exp_and_p(float ux, float uy, float s,
                                          float E[9], float p[3]) {
    float th2   = ux * ux + uy * uy;
    float theta = sqrtf(th2);
    float A, Bv, c;
    if (theta < 1e-5f) {
        A  = s;
        Bv = 0.5f * s * s;
        c  = 1.0f;
    } else {
        float phi = s * theta;              // phi <= ~2.7 rad
        float sh, ch;
        __sincosf(0.5f * phi, &sh, &ch);    // native v_sin/v_cos
        float si  = 2.0f * sh * ch;         // sin(phi)
        float sh2 = 2.0f * sh * sh;         // 1 - cos(phi), no cancellation
        float rth = fast_rcp(theta);
        A  = si * rth;
        Bv = sh2 * rth * rth;
        c  = 1.0f - sh2;
    }
    float Aux = A * ux, Auy = A * uy;
    E[0] = 1.0f - Bv * uy * uy;
    E[1] = Bv * ux * uy;
    E[2] = Auy;
    E[3] = E[1];
    E[4] = 1.0f - Bv * ux * ux;
    E[5] = -Aux;
    E[6] = -Auy;
    E[7] = Aux;
    E[8] = c;
    p[0] = Bv * uy;
    p[1] = -Bv * ux;
    p[2] = A;
}

__device__ __forceinline__ void compose(const float r0[3], const float R0[9],
                                        const float E[9], const float p[3],
                                        float r[3], float R[9]) {
#pragma unroll
    for (int i = 0; i < 3; ++i) {
        r[i] = r0[i] + R0[3*i+0] * p[0] + R0[3*i+1] * p[1] + R0[3*i+2] * p[2];
#pragma unroll
        for (int j = 0; j < 3; ++j) {
            R[3*i+j] = R0[3*i+0] * E[j] + R0[3*i+1] * E[3+j] + R0[3*i+2] * E[6+j];
        }
    }
}

__global__ __launch_bounds__(256) void rollout(const float* __restrict__ actions,
                                               float* __restrict__ out, int B) {
    __shared__ float sact[256 * 9];    // staged actions for this chunk
    __shared__ float sbuf[256 * 14];   // one output row slab

    const int tid   = threadIdx.x;
    const int chunk = blockIdx.x;          // batch chunk of 256
    const int n     = blockIdx.y / kGS;    // segment (uniform)
    const int gs    = blockIdx.y - n * kGS;// row-group within segment (uniform)
    const int tlo   = (kT * gs) / kGS;     // rows [tlo, thi) of segment n
    const int thi   = (kT * (gs + 1)) / kGS;

    // ---- stage 256x9 actions, fully coalesced (2304 floats = 576 float4)
    {
        const f32x4* a4 = reinterpret_cast<const f32x4*>(
            actions + (size_t)chunk * 256 * 9);
        f32x4* s4 = reinterpret_cast<f32x4*>(sact);
        s4[tid]       = a4[tid];
        s4[tid + 256] = a4[tid + 256];
        if (tid < 64) s4[tid + 512] = a4[tid + 512];
    }
    __syncthreads();

    // ---- walk chain in registers up to segment n (static unroll, uniform
    // guards; no runtime-indexed arrays -> everything stays in VGPRs)
    float r0[3] = {0.f, 0.f, 0.f};
    float R0[9] = {1.f, 0.f, 0.f, 0.f, 1.f, 0.f, 0.f, 0.f, 1.f};
    float sux = 0.f, suy = 0.f;
    int   skmax = 0;

#pragma unroll
    for (int m = 0; m < kNSeg; ++m) {
        if (m <= n) {
            const float a0 = sact[tid * 9 + 3 * m + 0];
            const float a1 = sact[tid * 9 + 3 * m + 1];
            const float a2 = sact[tid * 9 + 3 * m + 2];
            float l  = kL0 + a0;            // f32 add, matches jnp
            float md = l * kD;
            float ux = a2 / (-md);          // exact IEEE div (output-critical)
            float uy = a1 / md;
            int   km = (int)(l / kDS);      // exact IEEE div + trunc
            if (m == n) {
                sux = ux; suy = uy; skmax = km;
            } else {
                float s = (float)km * kDS;
                float E[9], p[3], nr[3], NR[9];
                exp_and_p(ux, uy, s, E, p);
                compose(r0, R0, E, p, nr, NR);
#pragma unroll
                for (int i = 0; i < 3; ++i) r0[i] = nr[i];
#pragma unroll
                for (int i = 0; i < 9; ++i) R0[i] = NR[i];
            }
        }
    }

    // ---- emit rows [tlo, thi) of segment n
    f32x4* sb4 = reinterpret_cast<f32x4*>(sbuf);
    for (int t = tlo; t < thi; ++t) {      // uniform loop
        int   tc = t < skmax ? t : skmax;  // per-thread clamp
        float s  = (float)tc * kDS;

        float E[9], p[3], r[3], R[9];
        exp_and_p(sux, suy, s, E, p);
        compose(r0, R0, E, p, r, R);

        __syncthreads();                   // WAR: prev row's copy-out done
        float* my = &sbuf[tid * 14];
        my[0] = r[0];  my[1] = r[1];  my[2] = r[2];
#pragma unroll
        for (int i = 0; i < 9; ++i) my[3 + i] = R[i];
        my[12] = sux;
        my[13] = suy;
        __syncthreads();                   // RAW: slab complete

        // coalesced NT store of the contiguous 14336B row slab
        size_t base = ((size_t)(n * kT + t) * (size_t)B
                       + (size_t)chunk * 256) * 14;
        f32x4* o4 = reinterpret_cast<f32x4*>(out + base);
#pragma unroll
        for (int k = 0; k < 3; ++k) {
            int q = k * 256 + tid;
            __builtin_nontemporal_store(sb4[q], &o4[q]);
        }
        if (tid < 128) {
            int q = 768 + tid;
            __builtin_nontemporal_store(sb4[q], &o4[q]);
        }
    }
}

} // namespace

extern "C" void kernel_launch(void* const* d_in, const int* in_sizes, int n_in,
                              void* d_out, int out_size, void* d_ws, size_t ws_size,
                              hipStream_t stream) {
    const float* actions = (const float*)d_in[0];
    float* out = (float*)d_out;
    int B = in_sizes[0] / 9;                     // 16384
    dim3 block(256);
    dim3 grid(B / 256, kNSeg * kGS);             // (64, 18)
    rollout<<<grid, block, 0, stream>>>(actions, out, B);
}

// Round 11
// 89.398 us; speedup vs baseline: 1.0373x; 1.0185x over previous
//
#include <hip/hip_runtime.h>

// Closed-form constant-curvature rollout (R3 structure — best measured).
// State y = [r(3), R(9 row-major), ux, uy].
// Per segment: ux,uy const => R(s) = R0 * exp(s*uhat), uhat = skew((ux,uy,0)).
// exp(s*uhat) = I + A*uhat + B*uhat^2, A = sin(phi)/theta, B = (1-cos(phi))/theta^2.
// r(s) = r0 + R0 * (B*uy, -B*ux, A).
// Reference clamps at kmax = (int)(l/DS): s = min(t, kmax)*DS; next segment
// starts from the state at s_end = kmax*DS.
//
// One output row per block (grid 64 x 87), chain recomputed per block
// (uniform, cheap, inputs L2-resident). Block's 256x14 floats staged in LDS,
// one barrier, stored as coalesced plain float4.
// R11 change vs R3: __launch_bounds__(256, 6) — cap VGPRs (~85) to guarantee
// 6 blocks/CU (24 waves) instead of a possible VGPR-bound 4 blocks/CU.

namespace {

constexpr float kL0 = 0.1f;
constexpr float kD  = 0.0075f;
constexpr float kDS = 0.005f;
constexpr int   kT    = 29;   // round((0.1+0.04)/0.005)+1
constexpr int   kNSeg = 3;

__device__ __forceinline__ float fast_rcp(float x) {
    return __builtin_amdgcn_rcpf(x);   // v_rcp_f32, ~1 ulp
}

__device__ __forceinline__ void exp_and_p(float ux, float uy, float s,
                                          float E[9], float p[3]) {
    float th2   = ux * ux + uy * uy;
    float theta = sqrtf(th2);
    float A, Bv, c;
    if (theta < 1e-5f) {
        A  = s;
        Bv = 0.5f * s * s;
        c  = 1.0f;
    } else {
        float phi = s * theta;
        float sh, ch;
        __sincosf(0.5f * phi, &sh, &ch);   // native v_sin/v_cos, phi/2 <= ~1.4 rad
        float si  = 2.0f * sh * ch;        // sin(phi)
        float sh2 = 2.0f * sh * sh;        // 1 - cos(phi), no cancellation
        float rth = fast_rcp(theta);
        A  = si * rth;
        Bv = sh2 * rth * rth;
        c  = 1.0f - sh2;
    }
    float Aux = A * ux, Auy = A * uy;
    E[0] = 1.0f - Bv * uy * uy;
    E[1] = Bv * ux * uy;
    E[2] = Auy;
    E[3] = E[1];
    E[4] = 1.0f - Bv * ux * ux;
    E[5] = -Aux;
    E[6] = -Auy;
    E[7] = Aux;
    E[8] = c;
    p[0] = Bv * uy;
    p[1] = -Bv * ux;
    p[2] = A;
}

// Advance frame (r,R) through segment m evaluated at step index t (t>=kT
// means "to segment end"). Leaves ux,uy of this segment in out params.
__device__ __forceinline__ void seg_state(const float* __restrict__ actions,
                                          int b, int m, int t,
                                          float r[3], float R[9],
                                          float& ux, float& uy) {
    const float a0 = actions[(size_t)b * 9 + 3 * m + 0];
    const float a1 = actions[(size_t)b * 9 + 3 * m + 1];
    const float a2 = actions[(size_t)b * 9 + 3 * m + 2];
    float l  = kL0 + a0;          // f32 add, matches jnp
    float md = l * kD;
    ux = a2 / (-md);              // exact IEEE div: ux,uy are outputs
    uy = a1 / md;
    int kmax = (int)(l / kDS);    // exact IEEE div + trunc == astype(int32)
    int tc = t < kmax ? t : kmax;
    float s = (float)tc * kDS;

    float E[9], p[3];
    exp_and_p(ux, uy, s, E, p);

    float nr[3], NR[9];
#pragma unroll
    for (int i = 0; i < 3; ++i) {
        nr[i] = r[i] + R[3 * i + 0] * p[0] + R[3 * i + 1] * p[1] + R[3 * i + 2] * p[2];
#pragma unroll
        for (int j = 0; j < 3; ++j) {
            NR[3 * i + j] = R[3 * i + 0] * E[j]
                          + R[3 * i + 1] * E[3 + j]
                          + R[3 * i + 2] * E[6 + j];
        }
    }
#pragma unroll
    for (int i = 0; i < 3; ++i) r[i] = nr[i];
#pragma unroll
    for (int i = 0; i < 9; ++i) R[i] = NR[i];
}

__global__ __launch_bounds__(256, 6) void rollout(const float* __restrict__ actions,
                                                  float* __restrict__ out, int B) {
    __shared__ float smem[256 * 14];

    int b = blockIdx.x * blockDim.x + threadIdx.x;
    int row = blockIdx.y;         // 0..3*kT-1, uniform per block
    int n = row / kT;             // segment (uniform)
    int t = row - n * kT;         // step within segment (uniform)

    float r[3] = {0.f, 0.f, 0.f};
    float R[9] = {1.f, 0.f, 0.f, 0.f, 1.f, 0.f, 0.f, 0.f, 1.f};
    float ux, uy;

    // chain through completed segments (uniform branches; kmax <= 28 < kT)
    if (n >= 1) seg_state(actions, b, 0, kT, r, R, ux, uy);
    if (n >= 2) seg_state(actions, b, 1, kT, r, R, ux, uy);
    // current segment at (clamped) step t
    seg_state(actions, b, n, t, r, R, ux, uy);

    // stage this thread's 14 outputs in LDS (stride 14: 4-way conflicts, cheap)
    float* my = &smem[threadIdx.x * 14];
    my[0] = r[0];  my[1] = r[1];  my[2] = r[2];
#pragma unroll
    for (int i = 0; i < 9; ++i) my[3 + i] = R[i];
    my[12] = ux;
    my[13] = uy;
    __syncthreads();

    // coalesced block store: 256*14 floats = 896 float4 (16B-aligned base)
    size_t blockbase = ((size_t)row * (size_t)B + (size_t)blockIdx.x * 256) * 14;
    float4* o4 = reinterpret_cast<float4*>(out + blockbase);
    const float4* s4 = reinterpret_cast<const float4*>(smem);
#pragma unroll
    for (int k = 0; k < 3; ++k) {
        int q = k * 256 + threadIdx.x;
        o4[q] = s4[q];
    }
    if (threadIdx.x < 128) {
        int q = 768 + threadIdx.x;
        o4[q] = s4[q];
    }
}

} // namespace

extern "C" void kernel_launch(void* const* d_in, const int* in_sizes, int n_in,
                              void* d_out, int out_size, void* d_ws, size_t ws_size,
                              hipStream_t stream) {
    const float* actions = (const float*)d_in[0];
    float* out = (float*)d_out;
    int B = in_sizes[0] / 9;                 // 16384
    dim3 block(256);
    dim3 grid((B + 255) / 256, kNSeg * kT);  // (64, 87)
    rollout<<<grid, block, 0, stream>>>(actions, out, B);
}